// Round 4
// baseline (760.278 us; speedup 1.0000x reference)
//
#include <hip/hip_runtime.h>

#define NN 100000
#define NE 1600000
#define HD 128
#define NL 3
#define NG 64
#define NC 10

#define NPART 8
#define PSZ 12500          // nodes per partition
#define NCHUNK 64
#define CSZ 25000          // edges per chunk (NE / NCHUNK)

typedef unsigned short ushortT;
typedef unsigned int uintT;

using bf16x8 = __attribute__((ext_vector_type(8))) __bf16;
using f32x4  = __attribute__((ext_vector_type(4))) float;

__device__ __forceinline__ ushortT f2bf(float f) {
  unsigned int u = __float_as_uint(f);
  u += 0x7fffu + ((u >> 16) & 1u);
  return (ushortT)(u >> 16);
}
__device__ __forceinline__ float bf_lo(uintT u) { return __uint_as_float(u << 16); }
__device__ __forceinline__ float bf_hi(uintT u) { return __uint_as_float(u & 0xffff0000u); }
__device__ __forceinline__ uintT packbf2(float a, float b) {
  return (uintT)f2bf(a) | ((uintT)f2bf(b) << 16);
}

// ---------------- CSR build (no global atomics) ----------------
__global__ __launch_bounds__(256) void k_hist2(const int* __restrict__ dst, int* __restrict__ hist) {
  __shared__ int cnt[PSZ];
  int tid = threadIdx.x;
  int p = blockIdx.x & 7, c = blockIdx.x >> 3;
  for (int i = tid; i < PSZ; i += 256) cnt[i] = 0;
  __syncthreads();
  int lo = p * PSZ, hi = lo + PSZ;
  const int4* d4 = (const int4*)(dst + c * CSZ);
  for (int j = tid; j < CSZ / 4; j += 256) {
    int4 v = d4[j];
    if (v.x >= lo && v.x < hi) atomicAdd(&cnt[v.x - lo], 1);
    if (v.y >= lo && v.y < hi) atomicAdd(&cnt[v.y - lo], 1);
    if (v.z >= lo && v.z < hi) atomicAdd(&cnt[v.z - lo], 1);
    if (v.w >= lo && v.w < hi) atomicAdd(&cnt[v.w - lo], 1);
  }
  __syncthreads();
  int* out = hist + (size_t)(p * NCHUNK + c) * PSZ;
  for (int i = tid; i < PSZ; i += 256) out[i] = cnt[i];
}

__global__ __launch_bounds__(256) void k_chunkscan(const int* __restrict__ hist, int* __restrict__ Boff,
                                                   int* __restrict__ deg) {
  int n = blockIdx.x * 256 + threadIdx.x;
  if (n >= NN) return;
  int p = n / PSZ, i = n % PSZ;
  int s = 0;
#pragma unroll 4
  for (int c = 0; c < NCHUNK; ++c) {
    size_t idx = (size_t)(p * NCHUNK + c) * PSZ + i;
    int v = hist[idx];
    Boff[idx] = s;
    s += v;
  }
  deg[n] = s;
}

__global__ void k_scan1(const int* __restrict__ deg, int* __restrict__ incl, int* __restrict__ bsum) {
  __shared__ int sh[256];
  int t = threadIdx.x;
  int base = blockIdx.x * 1024 + t * 4;
  int v[4]; int s = 0;
#pragma unroll
  for (int j = 0; j < 4; ++j) { int idx = base + j; v[j] = (idx < NN) ? deg[idx] : 0; s += v[j]; }
  sh[t] = s;
  __syncthreads();
  for (int off = 1; off < 256; off <<= 1) {
    int x = (t >= off) ? sh[t - off] : 0;
    __syncthreads();
    sh[t] += x;
    __syncthreads();
  }
  int run = sh[t] - s;
#pragma unroll
  for (int j = 0; j < 4; ++j) { run += v[j]; int idx = base + j; if (idx < NN) incl[idx] = run; }
  if (t == 255) bsum[blockIdx.x] = sh[255];
}

__global__ void k_scan2(const int* __restrict__ bsum, int* __restrict__ boff, int nb) {
  if (threadIdx.x == 0 && blockIdx.x == 0) {
    int run = 0;
    for (int j = 0; j < nb; ++j) { boff[j] = run; run += bsum[j]; }
  }
}

__global__ void k_scan3(const int* __restrict__ incl, const int* __restrict__ boff,
                        int* __restrict__ row_ptr) {
  int i = blockIdx.x * 256 + threadIdx.x;
  if (i < NN) {
    row_ptr[i + 1] = boff[i >> 10] + incl[i];
    if (i == 0) row_ptr[0] = 0;
  }
}

__global__ __launch_bounds__(256) void k_scatter2(const int* __restrict__ src, const int* __restrict__ dst,
                                                  const int* __restrict__ rowp, const int* __restrict__ Boff,
                                                  int* __restrict__ srt) {
  __shared__ int cur[PSZ];
  int tid = threadIdx.x;
  int p = blockIdx.x & 7, c = blockIdx.x >> 3;
  const int* bo = Boff + (size_t)(p * NCHUNK + c) * PSZ;
  const int* rp = rowp + p * PSZ;
  for (int i = tid; i < PSZ; i += 256) cur[i] = rp[i] + bo[i];
  __syncthreads();
  int lo = p * PSZ, hi = lo + PSZ;
  const int4* d4 = (const int4*)(dst + c * CSZ);
  const int4* s4 = (const int4*)(src + c * CSZ);
  for (int j = tid; j < CSZ / 4; j += 256) {
    int4 d = d4[j];
    int4 s = s4[j];
    if (d.x >= lo && d.x < hi) srt[atomicAdd(&cur[d.x - lo], 1)] = s.x;
    if (d.y >= lo && d.y < hi) srt[atomicAdd(&cur[d.y - lo], 1)] = s.y;
    if (d.z >= lo && d.z < hi) srt[atomicAdd(&cur[d.z - lo], 1)] = s.z;
    if (d.w >= lo && d.w < hi) srt[atomicAdd(&cur[d.w - lo], 1)] = s.w;
  }
}

// ---------------- conversions ----------------
__global__ void k_convw(const float* __restrict__ W1, const float* __restrict__ W2,
                        ushortT* __restrict__ Wt) {
  int idx = blockIdx.x * 256 + threadIdx.x;
  if (idx >= 6 * 16384) return;
  int mat = idx >> 14;
  int e = idx & 16383;
  int k = e >> 7, n = e & 127;
  int l = mat >> 1, w2 = mat & 1;
  const float* W = w2 ? W2 : W1;
  float v = W[l * 16384 + k * 128 + n];
  Wt[mat * 16384 + n * 128 + k] = f2bf(v);
}

__global__ void k_convx(const float* __restrict__ x, uintT* __restrict__ h) {
  int i = blockIdx.x * 256 + threadIdx.x;
  float2 v = ((const float2*)x)[i];
  h[i] = packbf2(v.x, v.y);
}

// ---------------- fused layer: gather + MLP(2 GEMMs) + BN, one kernel ----------------
__device__ __forceinline__ void mfma_128(const ushortT* As, const ushortT* Bs,
                                         f32x4 acc[2][8], int wave, int lane) {
  int col0 = lane & 15, q = lane >> 4;
  int mA = wave * 32 + col0;
  int mB = mA + 16;
#pragma unroll
  for (int kk = 0; kk < 4; ++kk) {
    int kc = kk * 4 + q;
    bf16x8 a0 = *(const bf16x8*)(&As[(mA * 16 + (kc ^ (mA & 15))) * 8]);
    bf16x8 a1 = *(const bf16x8*)(&As[(mB * 16 + (kc ^ (mB & 15))) * 8]);
#pragma unroll
    for (int t = 0; t < 8; ++t) {
      int n = t * 16 + col0;
      bf16x8 b = *(const bf16x8*)(&Bs[(n * 16 + (kc ^ (n & 15))) * 8]);
      acc[0][t] = __builtin_amdgcn_mfma_f32_16x16x32_bf16(a0, b, acc[0][t], 0, 0, 0);
      acc[1][t] = __builtin_amdgcn_mfma_f32_16x16x32_bf16(a1, b, acc[1][t], 0, 0, 0);
    }
  }
}

__global__ __launch_bounds__(256, 2) void k_layer(const uintT* __restrict__ h, const int* __restrict__ rowp,
                                                  const int* __restrict__ srt, const float* __restrict__ epsp,
                                                  int l, const ushortT* __restrict__ Wt1,
                                                  const ushortT* __restrict__ Wt2,
                                                  const float* __restrict__ b1v, const float* __restrict__ b2v,
                                                  const float* __restrict__ gammav, const float* __restrict__ betav,
                                                  const float* __restrict__ rmean, const float* __restrict__ rvar,
                                                  ushortT* __restrict__ hout) {
  __shared__ ushortT As[128 * 128];
  __shared__ ushortT Bs[128 * 128];
  int tid = threadIdx.x;
  int wave = tid >> 6, lane = tid & 63;
  int m0 = blockIdx.x * 128;

  // stage Bs = W1 while gather runs
#pragma unroll
  for (int it = 0; it < 8; ++it) {
    int c = it * 256 + tid;
    int n = c >> 4, c8 = c & 15;
    uint4 v = *(const uint4*)(Wt1 + n * 128 + c8 * 8);
    *(uint4*)(&Bs[(n * 16 + (c8 ^ (n & 15))) * 8]) = v;
  }

  // gather phase: wave handles 32 nodes, z row -> As (bf16, swizzled)
  float sc = 1.0f + epsp[l];
  for (int i = 0; i < 32; ++i) {
    int r = wave * 32 + i;           // local row
    int node = m0 + r;
    float a0 = 0.0f, a1 = 0.0f;
    if (node < NN) {
      uintT u = h[(size_t)node * 64 + lane];
      a0 = bf_lo(u) * sc;
      a1 = bf_hi(u) * sc;
      int e0 = rowp[node], e1 = rowp[node + 1];
      for (int base = e0; base < e1; base += 64) {
        int n = e1 - base; if (n > 64) n = 64;
        int idxv = 0;
        if (base + lane < e1) idxv = srt[base + lane];
        int j = 0;
        for (; j + 7 < n; j += 8) {
          const uintT* r0 = h + (size_t)__builtin_amdgcn_readlane(idxv, j + 0) * 64;
          const uintT* r1 = h + (size_t)__builtin_amdgcn_readlane(idxv, j + 1) * 64;
          const uintT* r2 = h + (size_t)__builtin_amdgcn_readlane(idxv, j + 2) * 64;
          const uintT* r3 = h + (size_t)__builtin_amdgcn_readlane(idxv, j + 3) * 64;
          const uintT* r4 = h + (size_t)__builtin_amdgcn_readlane(idxv, j + 4) * 64;
          const uintT* r5 = h + (size_t)__builtin_amdgcn_readlane(idxv, j + 5) * 64;
          const uintT* r6 = h + (size_t)__builtin_amdgcn_readlane(idxv, j + 6) * 64;
          const uintT* r7 = h + (size_t)__builtin_amdgcn_readlane(idxv, j + 7) * 64;
          uintT v0 = r0[lane], v1 = r1[lane], v2 = r2[lane], v3 = r3[lane];
          uintT v4 = r4[lane], v5 = r5[lane], v6 = r6[lane], v7 = r7[lane];
          a0 += ((bf_lo(v0) + bf_lo(v1)) + (bf_lo(v2) + bf_lo(v3))) +
                ((bf_lo(v4) + bf_lo(v5)) + (bf_lo(v6) + bf_lo(v7)));
          a1 += ((bf_hi(v0) + bf_hi(v1)) + (bf_hi(v2) + bf_hi(v3))) +
                ((bf_hi(v4) + bf_hi(v5)) + (bf_hi(v6) + bf_hi(v7)));
        }
        for (; j + 3 < n; j += 4) {
          const uintT* r0 = h + (size_t)__builtin_amdgcn_readlane(idxv, j + 0) * 64;
          const uintT* r1 = h + (size_t)__builtin_amdgcn_readlane(idxv, j + 1) * 64;
          const uintT* r2 = h + (size_t)__builtin_amdgcn_readlane(idxv, j + 2) * 64;
          const uintT* r3 = h + (size_t)__builtin_amdgcn_readlane(idxv, j + 3) * 64;
          uintT v0 = r0[lane], v1 = r1[lane], v2 = r2[lane], v3 = r3[lane];
          a0 += (bf_lo(v0) + bf_lo(v1)) + (bf_lo(v2) + bf_lo(v3));
          a1 += (bf_hi(v0) + bf_hi(v1)) + (bf_hi(v2) + bf_hi(v3));
        }
        for (; j < n; ++j) {
          const uintT* r0 = h + (size_t)__builtin_amdgcn_readlane(idxv, j) * 64;
          uintT v0 = r0[lane];
          a0 += bf_lo(v0);
          a1 += bf_hi(v0);
        }
      }
    }
    // col = 2*lane; chunk c8 = lane>>2; uint slot within chunk = lane&3
    ((uintT*)As)[(r * 16 + ((lane >> 2) ^ (r & 15))) * 4 + (lane & 3)] = packbf2(a0, a1);
  }
  __syncthreads();

  int col0 = lane & 15, q = lane >> 4;
  f32x4 acc[2][8];
#pragma unroll
  for (int s = 0; s < 2; ++s)
#pragma unroll
    for (int t = 0; t < 8; ++t) acc[s][t] = (f32x4)(0.0f);
  mfma_128(As, Bs, acc, wave, lane);
  __syncthreads();   // all waves done reading As/Bs

  // epilogue1: As = relu(acc + b1) (bf16, same swizzled layout); restage Bs = W2
#pragma unroll
  for (int t = 0; t < 8; ++t) {
    int n = t * 16 + col0;
    float bi = b1v[n];
#pragma unroll
    for (int sub = 0; sub < 2; ++sub) {
#pragma unroll
      for (int r = 0; r < 4; ++r) {
        int row = wave * 32 + sub * 16 + q * 4 + r;   // local row
        float v = fmaxf(acc[sub][t][r] + bi, 0.0f);
        As[(row * 16 + ((n >> 3) ^ (row & 15))) * 8 + (n & 7)] = f2bf(v);
      }
    }
  }
#pragma unroll
  for (int it = 0; it < 8; ++it) {
    int c = it * 256 + tid;
    int n = c >> 4, c8 = c & 15;
    uint4 v = *(const uint4*)(Wt2 + n * 128 + c8 * 8);
    *(uint4*)(&Bs[(n * 16 + (c8 ^ (n & 15))) * 8]) = v;
  }
  __syncthreads();

#pragma unroll
  for (int s = 0; s < 2; ++s)
#pragma unroll
    for (int t = 0; t < 8; ++t) acc[s][t] = (f32x4)(0.0f);
  mfma_128(As, Bs, acc, wave, lane);

  // epilogue2: hout = relu(BN(relu(acc + b2)))
#pragma unroll
  for (int t = 0; t < 8; ++t) {
    int n = t * 16 + col0;
    float bi = b2v[n];
    float scn = gammav[n] * rsqrtf(rvar[n] + 1e-5f);
    float o = betav[n] - rmean[n] * scn;
#pragma unroll
    for (int sub = 0; sub < 2; ++sub) {
#pragma unroll
      for (int r = 0; r < 4; ++r) {
        int row = m0 + wave * 32 + sub * 16 + q * 4 + r;
        if (row < NN) {
          float v = fmaxf(acc[sub][t][r] + bi, 0.0f);
          v = fmaxf(fmaf(v, scn, o), 0.0f);
          hout[(size_t)row * 128 + n] = f2bf(v);
        }
      }
    }
  }
}

// ---------------- pooling ----------------
__global__ __launch_bounds__(256) void k_pool(const uintT* __restrict__ h, const int* __restrict__ batch,
                                              float* __restrict__ pooled) {
  int t = threadIdx.x & 63;
  int wv = threadIdx.x >> 6;
  int s = blockIdx.x * 128 + wv * 32;
  int e = s + 32; if (e > NN) e = NN;
  if (s >= NN) return;
  float a0 = 0.0f, a1 = 0.0f;
  int curg = -1;
  for (int i = s; i < e; ++i) {
    int g = batch[i];
    if (g != curg) {
      if (curg >= 0) {
        atomicAdd(&pooled[curg * 128 + 2 * t], a0);
        atomicAdd(&pooled[curg * 128 + 2 * t + 1], a1);
      }
      curg = g; a0 = 0.0f; a1 = 0.0f;
    }
    uintT v = h[(size_t)i * 64 + t];
    a0 += bf_lo(v);
    a1 += bf_hi(v);
  }
  if (curg >= 0) {
    atomicAdd(&pooled[curg * 128 + 2 * t], a0);
    atomicAdd(&pooled[curg * 128 + 2 * t + 1], a1);
  }
}

// ---------------- head ----------------
__global__ __launch_bounds__(128) void k_head(const float* __restrict__ pooled,
                                              const float* __restrict__ w1, const float* __restrict__ b1,
                                              const float* __restrict__ w2, const float* __restrict__ b2,
                                              const float* __restrict__ w3, const float* __restrict__ b3,
                                              float* __restrict__ out) {
  __shared__ float p[128], y1[128], y2[64], lg[NC], lse;
  int g = blockIdx.x, t = threadIdx.x;
  p[t] = pooled[g * 128 + t];
  __syncthreads();
  float acc = b1[t];
  for (int k = 0; k < 128; ++k) acc = fmaf(p[k], w1[k * 128 + t], acc);
  y1[t] = fmaxf(acc, 0.0f);
  __syncthreads();
  if (t < 64) {
    float a = b2[t];
    for (int k = 0; k < 128; ++k) a = fmaf(y1[k], w2[k * 64 + t], a);
    y2[t] = fmaxf(a, 0.0f);
  }
  __syncthreads();
  if (t < NC) {
    float a = b3[t];
    for (int k = 0; k < 64; ++k) a = fmaf(y2[k], w3[k * NC + t], a);
    lg[t] = a;
  }
  __syncthreads();
  if (t == 0) {
    float m = -1e30f;
    for (int j = 0; j < NC; ++j) m = fmaxf(m, lg[j]);
    float sum = 0.0f;
    for (int j = 0; j < NC; ++j) sum += expf(lg[j] - m);
    lse = m + logf(sum);
  }
  __syncthreads();
  if (t < NC) out[g * NC + t] = lg[t] - lse;
}

// ---------------- launch ----------------
extern "C" void kernel_launch(void* const* d_in, const int* in_sizes, int n_in,
                              void* d_out, int out_size, void* d_ws, size_t ws_size,
                              hipStream_t stream) {
  const float* x     = (const float*)d_in[0];
  const int*   ei    = (const int*)d_in[1];
  const int*   srcp  = ei;
  const int*   dstp  = ei + NE;
  const int*   batch = (const int*)d_in[2];
  const float* eps   = (const float*)d_in[3];
  const float* W1    = (const float*)d_in[4];
  const float* b1    = (const float*)d_in[5];
  const float* W2    = (const float*)d_in[6];
  const float* b2    = (const float*)d_in[7];
  const float* gam   = (const float*)d_in[8];
  const float* bet   = (const float*)d_in[9];
  const float* rm    = (const float*)d_in[10];
  const float* rv    = (const float*)d_in[11];
  const float* fc1w  = (const float*)d_in[12];
  const float* fc1b  = (const float*)d_in[13];
  const float* fc2w  = (const float*)d_in[14];
  const float* fc2b  = (const float*)d_in[15];
  const float* fc3w  = (const float*)d_in[16];
  const float* fc3b  = (const float*)d_in[17];
  float* out = (float*)d_out;

  char* w = (char*)d_ws;
  uintT* bufA   = (uintT*)w;               w += (size_t)NN * 64 * 4;   // 25.6 MB
  uintT* bufB   = (uintT*)w;               w += (size_t)NN * 64 * 4;   // 25.6 MB
  int*   srt    = (int*)w;                 w += (size_t)NE * 4;        // 6.4 MB
  int*   rowp   = (int*)w;                 w += 400128;
  int*   deg    = (int*)w;                 w += 400128;
  int*   incl   = (int*)w;                 w += 400128;
  int*   bsum   = (int*)w;                 w += 2048;
  int*   boff   = (int*)w;                 w += 2048;
  ushortT* Wt   = (ushortT*)w;             w += 6 * 16384 * 2;
  float* pooled = (float*)w;               w += NG * HD * 4;

  // hist/Boff alias bufA/bufB (dead before conversions run): 8*64*12500*4 = 25.6 MB each
  int* hist = (int*)bufA;
  int* Boff = (int*)bufB;

  hipMemsetAsync(pooled, 0, (size_t)NG * HD * 4, stream);

  k_hist2<<<dim3(NPART * NCHUNK), dim3(256), 0, stream>>>(dstp, hist);
  k_chunkscan<<<dim3((NN + 255) / 256), dim3(256), 0, stream>>>(hist, Boff, deg);
  int nb = (NN + 1023) / 1024;
  k_scan1<<<dim3(nb), dim3(256), 0, stream>>>(deg, incl, bsum);
  k_scan2<<<dim3(1), dim3(64), 0, stream>>>(bsum, boff, nb);
  k_scan3<<<dim3((NN + 255) / 256), dim3(256), 0, stream>>>(incl, boff, rowp);
  k_scatter2<<<dim3(NPART * NCHUNK), dim3(256), 0, stream>>>(srcp, dstp, rowp, Boff, srt);

  k_convw<<<dim3(384), dim3(256), 0, stream>>>(W1, W2, Wt);
  k_convx<<<dim3(NN * 64 / 256), dim3(256), 0, stream>>>(x, bufA);

  int grid = (NN + 127) / 128;  // 782
  // alternate bufA -> bufB -> bufA -> bufB
  const uintT* hin = bufA;
  uintT* hout = bufB;
  for (int l = 0; l < NL; ++l) {
    k_layer<<<dim3(grid), dim3(256), 0, stream>>>(hin, rowp, srt, eps, l,
                                                  Wt + (2 * l) * 16384, Wt + (2 * l + 1) * 16384,
                                                  b1 + l * 128, b2 + l * 128,
                                                  gam + l * 128, bet + l * 128,
                                                  rm + l * 128, rv + l * 128,
                                                  (ushortT*)hout);
    const uintT* tmp = hin; hin = hout; hout = (uintT*)tmp;
  }
  // after 3 layers: result is in bufB (A->B, B->A, A->B)

  k_pool<<<dim3((NN + 127) / 128), dim3(256), 0, stream>>>(bufB, batch, pooled);
  k_head<<<dim3(NG), dim3(128), 0, stream>>>(pooled, fc1w, fc1b, fc2w, fc2b, fc3w, fc3b, out);
}

// Round 5
// 508.401 us; speedup vs baseline: 1.4954x; 1.4954x over previous
//
#include <hip/hip_runtime.h>

#define NN 100000
#define NE 1600000
#define HD 128
#define NL 3
#define NG 64
#define NC 10

#define NPART 8
#define PSZ 12500          // nodes per partition
#define NCHUNK 64
#define CSZ 25000          // edges per chunk (NE / NCHUNK)

typedef unsigned short ushortT;
typedef unsigned int uintT;

using bf16x8 = __attribute__((ext_vector_type(8))) __bf16;
using f32x4  = __attribute__((ext_vector_type(4))) float;

__device__ __forceinline__ ushortT f2bf(float f) {
  unsigned int u = __float_as_uint(f);
  u += 0x7fffu + ((u >> 16) & 1u);
  return (ushortT)(u >> 16);
}
__device__ __forceinline__ float bf_lo(uintT u) { return __uint_as_float(u << 16); }
__device__ __forceinline__ float bf_hi(uintT u) { return __uint_as_float(u & 0xffff0000u); }
__device__ __forceinline__ uintT packbf2(float a, float b) {
  return (uintT)f2bf(a) | ((uintT)f2bf(b) << 16);
}

// ---------------- CSR build (no global atomics; ushort hist/Boff) ----------------
__global__ __launch_bounds__(256) void k_hist2(const int* __restrict__ dst, ushortT* __restrict__ hist) {
  __shared__ int cnt[PSZ];
  int tid = threadIdx.x;
  int p = blockIdx.x & 7, c = blockIdx.x >> 3;
  for (int i = tid; i < PSZ; i += 256) cnt[i] = 0;
  __syncthreads();
  int lo = p * PSZ, hi = lo + PSZ;
  const int4* d4 = (const int4*)(dst + c * CSZ);
  for (int j = tid; j < CSZ / 4; j += 256) {
    int4 v = d4[j];
    if (v.x >= lo && v.x < hi) atomicAdd(&cnt[v.x - lo], 1);
    if (v.y >= lo && v.y < hi) atomicAdd(&cnt[v.y - lo], 1);
    if (v.z >= lo && v.z < hi) atomicAdd(&cnt[v.z - lo], 1);
    if (v.w >= lo && v.w < hi) atomicAdd(&cnt[v.w - lo], 1);
  }
  __syncthreads();
  ushortT* out = hist + (size_t)(p * NCHUNK + c) * PSZ;
  for (int i = tid; i < PSZ; i += 256) out[i] = (ushortT)cnt[i];
}

__global__ __launch_bounds__(256) void k_chunkscan(const ushortT* __restrict__ hist, ushortT* __restrict__ Boff,
                                                   int* __restrict__ deg) {
  int n = blockIdx.x * 256 + threadIdx.x;
  if (n >= NN) return;
  int p = n / PSZ, i = n % PSZ;
  int s = 0;
#pragma unroll 4
  for (int c = 0; c < NCHUNK; ++c) {
    size_t idx = (size_t)(p * NCHUNK + c) * PSZ + i;
    int v = hist[idx];
    Boff[idx] = (ushortT)s;
    s += v;
  }
  deg[n] = s;
}

__global__ void k_scan1(const int* __restrict__ deg, int* __restrict__ incl, int* __restrict__ bsum) {
  __shared__ int sh[256];
  int t = threadIdx.x;
  int base = blockIdx.x * 1024 + t * 4;
  int v[4]; int s = 0;
#pragma unroll
  for (int j = 0; j < 4; ++j) { int idx = base + j; v[j] = (idx < NN) ? deg[idx] : 0; s += v[j]; }
  sh[t] = s;
  __syncthreads();
  for (int off = 1; off < 256; off <<= 1) {
    int x = (t >= off) ? sh[t - off] : 0;
    __syncthreads();
    sh[t] += x;
    __syncthreads();
  }
  int run = sh[t] - s;
#pragma unroll
  for (int j = 0; j < 4; ++j) { run += v[j]; int idx = base + j; if (idx < NN) incl[idx] = run; }
  if (t == 255) bsum[blockIdx.x] = sh[255];
}

__global__ void k_scan2(const int* __restrict__ bsum, int* __restrict__ boff, int nb) {
  if (threadIdx.x == 0 && blockIdx.x == 0) {
    int run = 0;
    for (int j = 0; j < nb; ++j) { boff[j] = run; run += bsum[j]; }
  }
}

__global__ void k_scan3(const int* __restrict__ incl, const int* __restrict__ boff,
                        int* __restrict__ row_ptr) {
  int i = blockIdx.x * 256 + threadIdx.x;
  if (i < NN) {
    row_ptr[i + 1] = boff[i >> 10] + incl[i];
    if (i == 0) row_ptr[0] = 0;
  }
}

__global__ __launch_bounds__(256) void k_scatter2(const int* __restrict__ src, const int* __restrict__ dst,
                                                  const int* __restrict__ rowp, const ushortT* __restrict__ Boff,
                                                  int* __restrict__ srt) {
  __shared__ int cur[PSZ];
  int tid = threadIdx.x;
  int p = blockIdx.x & 7, c = blockIdx.x >> 3;
  const ushortT* bo = Boff + (size_t)(p * NCHUNK + c) * PSZ;
  const int* rp = rowp + p * PSZ;
  for (int i = tid; i < PSZ; i += 256) cur[i] = rp[i] + (int)bo[i];
  __syncthreads();
  int lo = p * PSZ, hi = lo + PSZ;
  const int4* d4 = (const int4*)(dst + c * CSZ);
  const int4* s4 = (const int4*)(src + c * CSZ);
  for (int j = tid; j < CSZ / 4; j += 256) {
    int4 d = d4[j];
    int4 s = s4[j];
    if (d.x >= lo && d.x < hi) srt[atomicAdd(&cur[d.x - lo], 1)] = s.x;
    if (d.y >= lo && d.y < hi) srt[atomicAdd(&cur[d.y - lo], 1)] = s.y;
    if (d.z >= lo && d.z < hi) srt[atomicAdd(&cur[d.z - lo], 1)] = s.z;
    if (d.w >= lo && d.w < hi) srt[atomicAdd(&cur[d.w - lo], 1)] = s.w;
  }
}

// ---------------- conversions ----------------
__global__ void k_convw(const float* __restrict__ W1, const float* __restrict__ W2,
                        ushortT* __restrict__ Wt) {
  int idx = blockIdx.x * 256 + threadIdx.x;
  if (idx >= 6 * 16384) return;
  int mat = idx >> 14;
  int e = idx & 16383;
  int k = e >> 7, n = e & 127;
  int l = mat >> 1, w2 = mat & 1;
  const float* W = w2 ? W2 : W1;
  float v = W[l * 16384 + k * 128 + n];
  Wt[mat * 16384 + n * 128 + k] = f2bf(v);
}

__global__ void k_convx(const float* __restrict__ x, uintT* __restrict__ h) {
  int i = blockIdx.x * 256 + threadIdx.x;
  float2 v = ((const float2*)x)[i];
  h[i] = packbf2(v.x, v.y);
}

// ---------------- aggregation: wide (dwordx4) gather ----------------
// One wave per node. 4 rows per load instruction: lane group g=lane>>4 takes
// row j+g, reading 16B chunk c16=lane&15. Cross-group reduce via shfl_xor.
#define GATHER4(J, V, M)                                                          \
  {                                                                               \
    int i0 = __builtin_amdgcn_readlane(idxv, (J) + 0);                            \
    int i1 = __builtin_amdgcn_readlane(idxv, (J) + 1);                            \
    int i2 = __builtin_amdgcn_readlane(idxv, (J) + 2);                            \
    int i3 = __builtin_amdgcn_readlane(idxv, (J) + 3);                            \
    int r01 = (g & 1) ? i1 : i0;                                                  \
    int r23 = (g & 1) ? i3 : i2;                                                  \
    int row = (g & 2) ? r23 : r01;                                                \
    M = ((J) + g < n) ? 1.0f : 0.0f;                                              \
    V = *(const uint4*)((const char*)h + ((size_t)(unsigned)row << 8) + (c16 << 4)); \
  }

__global__ __launch_bounds__(256) void k_agg(const uintT* __restrict__ h, const int* __restrict__ rowp,
                                             const int* __restrict__ srt, const float* __restrict__ epsp,
                                             int l, uintT* __restrict__ z) {
  int node = blockIdx.x * 4 + (threadIdx.x >> 6);
  int lane = threadIdx.x & 63;
  int g = lane >> 4;
  int c16 = lane & 15;
  float sc = 1.0f + epsp[l];
  uint4 self = ((const uint4*)(h + (size_t)node * 64))[c16];
  float acc[8];
#pragma unroll
  for (int k = 0; k < 8; ++k) acc[k] = 0.0f;
  int e0 = rowp[node], e1 = rowp[node + 1];
  for (int base = e0; base < e1; base += 64) {
    int n = e1 - base; if (n > 64) n = 64;
    int idxv = 0;
    if (base + lane < e1) idxv = srt[base + lane];
    for (int j = 0; j < n; j += 16) {
      uint4 va, vb = make_uint4(0,0,0,0), vc = make_uint4(0,0,0,0), vd = make_uint4(0,0,0,0);
      float ma, mb = 0.0f, mc = 0.0f, md = 0.0f;
      GATHER4(j, va, ma);
      if (j + 4 < n)  GATHER4(j + 4, vb, mb);
      if (j + 8 < n)  GATHER4(j + 8, vc, mc);
      if (j + 12 < n) GATHER4(j + 12, vd, md);
      const uintT* pa = &va.x; const uintT* pb = &vb.x;
      const uintT* pc = &vc.x; const uintT* pd = &vd.x;
#pragma unroll
      for (int k = 0; k < 4; ++k) {
        acc[2 * k]     = fmaf(ma, bf_lo(pa[k]), acc[2 * k]);
        acc[2 * k + 1] = fmaf(ma, bf_hi(pa[k]), acc[2 * k + 1]);
        acc[2 * k]     = fmaf(mb, bf_lo(pb[k]), acc[2 * k]);
        acc[2 * k + 1] = fmaf(mb, bf_hi(pb[k]), acc[2 * k + 1]);
        acc[2 * k]     = fmaf(mc, bf_lo(pc[k]), acc[2 * k]);
        acc[2 * k + 1] = fmaf(mc, bf_hi(pc[k]), acc[2 * k + 1]);
        acc[2 * k]     = fmaf(md, bf_lo(pd[k]), acc[2 * k]);
        acc[2 * k + 1] = fmaf(md, bf_hi(pd[k]), acc[2 * k + 1]);
      }
    }
  }
  // cross-group reduce (groups differ in lane bits 4,5)
#pragma unroll
  for (int k = 0; k < 8; ++k) {
    acc[k] += __shfl_xor(acc[k], 16);
    acc[k] += __shfl_xor(acc[k], 32);
  }
  // self term
  const uintT* ps = &self.x;
#pragma unroll
  for (int k = 0; k < 4; ++k) {
    acc[2 * k]     = fmaf(sc, bf_lo(ps[k]), acc[2 * k]);
    acc[2 * k + 1] = fmaf(sc, bf_hi(ps[k]), acc[2 * k + 1]);
  }
  if (g == 0) {
    uint4 o;
    o.x = packbf2(acc[0], acc[1]);
    o.y = packbf2(acc[2], acc[3]);
    o.z = packbf2(acc[4], acc[5]);
    o.w = packbf2(acc[6], acc[7]);
    ((uint4*)(z + (size_t)node * 64))[c16] = o;
  }
}

// ---------------- fused MLP: relu(BN(relu(relu(Z@W1+b1)@W2+b2))) ----------------
__device__ __forceinline__ void mfma_128(const ushortT* As, const ushortT* Bs,
                                         f32x4 acc[2][8], int wave, int lane) {
  int col0 = lane & 15, q = lane >> 4;
  int mA = wave * 32 + col0;
  int mB = mA + 16;
#pragma unroll
  for (int kk = 0; kk < 4; ++kk) {
    int kc = kk * 4 + q;
    bf16x8 a0 = *(const bf16x8*)(&As[(mA * 16 + (kc ^ (mA & 15))) * 8]);
    bf16x8 a1 = *(const bf16x8*)(&As[(mB * 16 + (kc ^ (mB & 15))) * 8]);
#pragma unroll
    for (int t = 0; t < 8; ++t) {
      int n = t * 16 + col0;
      bf16x8 b = *(const bf16x8*)(&Bs[(n * 16 + (kc ^ (n & 15))) * 8]);
      acc[0][t] = __builtin_amdgcn_mfma_f32_16x16x32_bf16(a0, b, acc[0][t], 0, 0, 0);
      acc[1][t] = __builtin_amdgcn_mfma_f32_16x16x32_bf16(a1, b, acc[1][t], 0, 0, 0);
    }
  }
}

__global__ __launch_bounds__(256, 2) void k_mlp(const ushortT* __restrict__ Z,
                                                const ushortT* __restrict__ Wt1,
                                                const ushortT* __restrict__ Wt2,
                                                const float* __restrict__ b1v, const float* __restrict__ b2v,
                                                const float* __restrict__ gammav, const float* __restrict__ betav,
                                                const float* __restrict__ rmean, const float* __restrict__ rvar,
                                                ushortT* __restrict__ hout) {
  __shared__ ushortT As[128 * 128];
  __shared__ ushortT Bs[128 * 128];
  int tid = threadIdx.x;
  int wave = tid >> 6, lane = tid & 63;
  int m0 = blockIdx.x * 128;

#pragma unroll
  for (int it = 0; it < 8; ++it) {
    int c = it * 256 + tid;
    int n = c >> 4, c8 = c & 15;
    uint4 v = *(const uint4*)(Wt1 + n * 128 + c8 * 8);
    *(uint4*)(&Bs[(n * 16 + (c8 ^ (n & 15))) * 8]) = v;
  }
#pragma unroll
  for (int it = 0; it < 8; ++it) {
    int c = it * 256 + tid;
    int r = c >> 4, c8 = c & 15;
    int gm = m0 + r;
    uint4 v = make_uint4(0u, 0u, 0u, 0u);
    if (gm < NN) v = *(const uint4*)(Z + (size_t)gm * 128 + c8 * 8);
    *(uint4*)(&As[(r * 16 + (c8 ^ (r & 15))) * 8]) = v;
  }
  __syncthreads();

  int col0 = lane & 15, q = lane >> 4;
  f32x4 acc[2][8];
#pragma unroll
  for (int s = 0; s < 2; ++s)
#pragma unroll
    for (int t = 0; t < 8; ++t) acc[s][t] = (f32x4)(0.0f);
  mfma_128(As, Bs, acc, wave, lane);
  __syncthreads();   // all waves done reading As/Bs

  // epilogue1: As = relu(acc + b1); restage Bs = W2
#pragma unroll
  for (int t = 0; t < 8; ++t) {
    int n = t * 16 + col0;
    float bi = b1v[n];
#pragma unroll
    for (int sub = 0; sub < 2; ++sub) {
#pragma unroll
      for (int r = 0; r < 4; ++r) {
        int row = wave * 32 + sub * 16 + q * 4 + r;
        float v = fmaxf(acc[sub][t][r] + bi, 0.0f);
        As[(row * 16 + ((n >> 3) ^ (row & 15))) * 8 + (n & 7)] = f2bf(v);
      }
    }
  }
#pragma unroll
  for (int it = 0; it < 8; ++it) {
    int c = it * 256 + tid;
    int n = c >> 4, c8 = c & 15;
    uint4 v = *(const uint4*)(Wt2 + n * 128 + c8 * 8);
    *(uint4*)(&Bs[(n * 16 + (c8 ^ (n & 15))) * 8]) = v;
  }
  __syncthreads();

#pragma unroll
  for (int s = 0; s < 2; ++s)
#pragma unroll
    for (int t = 0; t < 8; ++t) acc[s][t] = (f32x4)(0.0f);
  mfma_128(As, Bs, acc, wave, lane);

  // epilogue2: hout = relu(BN(relu(acc + b2)))
#pragma unroll
  for (int t = 0; t < 8; ++t) {
    int n = t * 16 + col0;
    float bi = b2v[n];
    float scn = gammav[n] * rsqrtf(rvar[n] + 1e-5f);
    float o = betav[n] - rmean[n] * scn;
#pragma unroll
    for (int sub = 0; sub < 2; ++sub) {
#pragma unroll
      for (int r = 0; r < 4; ++r) {
        int row = m0 + wave * 32 + sub * 16 + q * 4 + r;
        if (row < NN) {
          float v = fmaxf(acc[sub][t][r] + bi, 0.0f);
          v = fmaxf(fmaf(v, scn, o), 0.0f);
          hout[(size_t)row * 128 + n] = f2bf(v);
        }
      }
    }
  }
}

// ---------------- pooling ----------------
__global__ __launch_bounds__(256) void k_pool(const uintT* __restrict__ h, const int* __restrict__ batch,
                                              float* __restrict__ pooled) {
  int t = threadIdx.x & 63;
  int wv = threadIdx.x >> 6;
  int s = blockIdx.x * 128 + wv * 32;
  int e = s + 32; if (e > NN) e = NN;
  if (s >= NN) return;
  float a0 = 0.0f, a1 = 0.0f;
  int curg = -1;
  for (int i = s; i < e; ++i) {
    int g = batch[i];
    if (g != curg) {
      if (curg >= 0) {
        atomicAdd(&pooled[curg * 128 + 2 * t], a0);
        atomicAdd(&pooled[curg * 128 + 2 * t + 1], a1);
      }
      curg = g; a0 = 0.0f; a1 = 0.0f;
    }
    uintT v = h[(size_t)i * 64 + t];
    a0 += bf_lo(v);
    a1 += bf_hi(v);
  }
  if (curg >= 0) {
    atomicAdd(&pooled[curg * 128 + 2 * t], a0);
    atomicAdd(&pooled[curg * 128 + 2 * t + 1], a1);
  }
}

// ---------------- head ----------------
__global__ __launch_bounds__(128) void k_head(const float* __restrict__ pooled,
                                              const float* __restrict__ w1, const float* __restrict__ b1,
                                              const float* __restrict__ w2, const float* __restrict__ b2,
                                              const float* __restrict__ w3, const float* __restrict__ b3,
                                              float* __restrict__ out) {
  __shared__ float p[128], y1[128], y2[64], lg[NC], lse;
  int g = blockIdx.x, t = threadIdx.x;
  p[t] = pooled[g * 128 + t];
  __syncthreads();
  float acc = b1[t];
  for (int k = 0; k < 128; ++k) acc = fmaf(p[k], w1[k * 128 + t], acc);
  y1[t] = fmaxf(acc, 0.0f);
  __syncthreads();
  if (t < 64) {
    float a = b2[t];
    for (int k = 0; k < 128; ++k) a = fmaf(y1[k], w2[k * 64 + t], a);
    y2[t] = fmaxf(a, 0.0f);
  }
  __syncthreads();
  if (t < NC) {
    float a = b3[t];
    for (int k = 0; k < 64; ++k) a = fmaf(y2[k], w3[k * NC + t], a);
    lg[t] = a;
  }
  __syncthreads();
  if (t == 0) {
    float m = -1e30f;
    for (int j = 0; j < NC; ++j) m = fmaxf(m, lg[j]);
    float sum = 0.0f;
    for (int j = 0; j < NC; ++j) sum += expf(lg[j] - m);
    lse = m + logf(sum);
  }
  __syncthreads();
  if (t < NC) out[g * NC + t] = lg[t] - lse;
}

// ---------------- launch ----------------
extern "C" void kernel_launch(void* const* d_in, const int* in_sizes, int n_in,
                              void* d_out, int out_size, void* d_ws, size_t ws_size,
                              hipStream_t stream) {
  const float* x     = (const float*)d_in[0];
  const int*   ei    = (const int*)d_in[1];
  const int*   srcp  = ei;
  const int*   dstp  = ei + NE;
  const int*   batch = (const int*)d_in[2];
  const float* eps   = (const float*)d_in[3];
  const float* W1    = (const float*)d_in[4];
  const float* b1    = (const float*)d_in[5];
  const float* W2    = (const float*)d_in[6];
  const float* b2    = (const float*)d_in[7];
  const float* gam   = (const float*)d_in[8];
  const float* bet   = (const float*)d_in[9];
  const float* rm    = (const float*)d_in[10];
  const float* rv    = (const float*)d_in[11];
  const float* fc1w  = (const float*)d_in[12];
  const float* fc1b  = (const float*)d_in[13];
  const float* fc2w  = (const float*)d_in[14];
  const float* fc2b  = (const float*)d_in[15];
  const float* fc3w  = (const float*)d_in[16];
  const float* fc3b  = (const float*)d_in[17];
  float* out = (float*)d_out;

  char* w = (char*)d_ws;
  uintT* bufA   = (uintT*)w;               w += (size_t)NN * 64 * 4;   // 25.6 MB
  uintT* bufB   = (uintT*)w;               w += (size_t)NN * 64 * 4;   // 25.6 MB
  int*   srt    = (int*)w;                 w += (size_t)NE * 4;        // 6.4 MB
  int*   rowp   = (int*)w;                 w += 400128;
  int*   deg    = (int*)w;                 w += 400128;
  int*   incl   = (int*)w;                 w += 400128;
  int*   bsum   = (int*)w;                 w += 2048;
  int*   boff   = (int*)w;                 w += 2048;
  ushortT* Wt   = (ushortT*)w;             w += 6 * 16384 * 2;
  float* pooled = (float*)w;               w += NG * HD * 4;

  // hist/Boff alias bufA/bufB (dead before conversions run): 8*64*12500*2 = 12.8 MB each
  ushortT* hist = (ushortT*)bufA;
  ushortT* Boff = (ushortT*)bufB;

  hipMemsetAsync(pooled, 0, (size_t)NG * HD * 4, stream);

  k_hist2<<<dim3(NPART * NCHUNK), dim3(256), 0, stream>>>(dstp, hist);
  k_chunkscan<<<dim3((NN + 255) / 256), dim3(256), 0, stream>>>(hist, Boff, deg);
  int nb = (NN + 1023) / 1024;
  k_scan1<<<dim3(nb), dim3(256), 0, stream>>>(deg, incl, bsum);
  k_scan2<<<dim3(1), dim3(64), 0, stream>>>(bsum, boff, nb);
  k_scan3<<<dim3((NN + 255) / 256), dim3(256), 0, stream>>>(incl, boff, rowp);
  k_scatter2<<<dim3(NPART * NCHUNK), dim3(256), 0, stream>>>(srcp, dstp, rowp, Boff, srt);

  k_convw<<<dim3(384), dim3(256), 0, stream>>>(W1, W2, Wt);
  k_convx<<<dim3(NN * 64 / 256), dim3(256), 0, stream>>>(x, bufA);

  int grid = (NN + 127) / 128;  // 782
  // h lives in bufA across layers; z in bufB
  for (int l = 0; l < NL; ++l) {
    k_agg<<<dim3(NN / 4), dim3(256), 0, stream>>>(bufA, rowp, srt, eps, l, bufB);
    k_mlp<<<dim3(grid), dim3(256), 0, stream>>>((const ushortT*)bufB,
                                                Wt + (2 * l) * 16384, Wt + (2 * l + 1) * 16384,
                                                b1 + l * 128, b2 + l * 128,
                                                gam + l * 128, bet + l * 128,
                                                rm + l * 128, rv + l * 128,
                                                (ushortT*)bufA);
  }

  k_pool<<<dim3((NN + 127) / 128), dim3(256), 0, stream>>>(bufA, batch, pooled);
  k_head<<<dim3(NG), dim3(128), 0, stream>>>(pooled, fc1w, fc1b, fc2w, fc2b, fc3w, fc3b, out);
}